// Round 2
// baseline (271.122 us; speedup 1.0000x reference)
//
#include <hip/hip_runtime.h>

// Backward (bilinear) warp: out[b,c,h,w] = bilinear_sample(input[b,c], w+flow_x, h+flow_y)
// Shapes: input [4,32,512,512] f32, flow [4,2,512,512] f32, out [4,32,512,512] f32.
//
// R4: break the single-barrier-domain serialization. R3 (95.7us/dispatch,
// VALUBusy 11%, HBM 35%) had 1 block/CU; every per-channel __syncthreads
// drained vmcnt(0) (incl. output stores) and stalled all 16 waves on the
// slowest. This version:
//  - 64x32 tiles, 512 threads, 512 blocks -> 2 blocks/CU (two independent
//    barrier domains; block B computes while block A waits on barriers/stage).
//  - single 96x128 staged buffer (48 KiB) per block; 2 blocks fit in LDS.
//  - raw s_barrier + counted waitcnt instead of __syncthreads:
//      gather -> lgkmcnt(0) -> barrier(WAR) -> stage(c+1) -> stores(c)
//      -> vmcnt(4) -> barrier(RAW)
//    stores are issued AFTER the 6 stage loads, so vmcnt(4) drains the stage
//    while leaving the 4 stores in flight -> stores never drained in-loop.
//  - bijective XCD swizzle: 64 contiguous tiles per XCD -> apron overlap of
//    adjacent tiles hits the same L2.

constexpr int B = 4, C = 32, H = 512, W = 512;
constexpr int HW = H * W;
constexpr int TW = 64, TH = 32;   // tile
constexpr int APRON = 31;         // covers |flow| <= ~31 (3.87 sigma of N(0,8))
constexpr int RH = 96;            // staged rows: 32 + 2*31 + 1 = 95 -> 96
constexpr int RW = 128;           // staged cols (dwords): 64 + 63 + 1 -> 128

typedef __attribute__((address_space(1))) const unsigned int gas_u32;
typedef __attribute__((address_space(3))) unsigned int las_u32;

__global__ __launch_bounds__(512, 4) void warp_tile_kernel(
    const float* __restrict__ input,
    const float* __restrict__ flow,
    float* __restrict__ out)
{
    __shared__ float s[RH * RW];          // 48 KiB, single buffer

    // XCD-aware bijective swizzle (512 blocks % 8 XCDs == 0):
    // each XCD gets 64 consecutive logical tiles (a full-width slab).
    int bid0 = (int)blockIdx.x;
    int bid = (bid0 & 7) * 64 + (bid0 >> 3);

    int tx = bid & 7;                     // [b:4][ty:16][tx:8]
    int ty = (bid >> 3) & 15;
    int b  = bid >> 7;
    int tx0 = tx * TW, ty0 = ty * TH;

    // virtual region origin (may be out of image; staging sources are clamped
    // per-lane, and clamped/garbage cells are provably never gathered)
    int rx0 = tx0 - 32;                   // 32 keeps RW=128 & 16B alignment
    int ry0 = ty0 - APRON;

    int tid  = (int)threadIdx.x;
    int lane = tid & 63;
    int wv   = tid >> 6;                  // wave id 0..7
    int cl   = tid & 63;                  // output col within tile
    int rl   = tid >> 6;                  // output row group (rows rl + 8p)

    // ---- staging source offsets (channel-relative dword offsets, per lane) ----
    // wave wv, issue i (0..5) stages region rows r=12*wv+2*i and r+1:
    //   lanes 0..31 -> row r cols 4L..4L+3, lanes 32..63 -> row r+1.
    int soff[6];
    int sr[6];
    {
        int lrow = lane >> 5;                        // 0 or 1
        int lc   = (lane & 31) << 2;                 // 0..124
        int gcol = min(max(rx0 + lc, 0), W - 4);     // 16B-aligned, in-row
        #pragma unroll
        for (int i = 0; i < 6; ++i) {
            int r = 12 * wv + 2 * i;                 // wave-uniform
            sr[i] = r;
            int grow = min(max(ry0 + r + lrow, 0), H - 1);
            soff[i] = grow * W + gcol;
        }
    }

    // ---- per-pixel precompute (4 px/thread), reused across 32 channels ----
    float wa[4], wb_[4], wc_[4], wd_[4];
    int a0[4], a1[4];
    int opix0 = (ty0 + rl) * W + tx0 + cl;

    #pragma unroll
    for (int p = 0; p < 4; ++p) {
        int h = ty0 + rl + 8 * p;
        int w = tx0 + cl;
        int pix = h * W + w;
        float fx = flow[(b * 2 + 0) * HW + pix];
        float fy = flow[(b * 2 + 1) * HW + pix];
        float x = fminf(fmaxf((float)w + fx, 0.0f), (float)(W - 1));
        float y = fminf(fmaxf((float)h + fy, 0.0f), (float)(H - 1));
        float x0f = floorf(x), y0f = floorf(y);
        int x0 = (int)x0f, y0 = (int)y0f;
        int y1 = min(y0 + 1, H - 1);
        float dx = x - x0f, dy = y - y0f;
        // weights use UNCLAMPED x1f=x0f+1, y1f=y0f+1 (matches reference)
        wa[p]  = (1.f - dx) * (1.f - dy);
        wb_[p] = (1.f - dx) * dy;
        wc_[p] = dx * (1.f - dy);
        wd_[p] = dx * dy;
        int ax0 = x0 - rx0, ay0 = y0 - ry0, ay1 = y1 - ry0;
        // need ax0 in [0,RW-2] (reads ax0+1), ay0>=0, ay1<=RH-1
        bool inreg = (ax0 >= 0) && (ax0 <= RW - 2) && (ay0 >= 0) && (ay1 <= RH - 1);
        // at x0==x1 (image right edge) the +1 read hits a staged-garbage col,
        // but its weight wc==dx==0 -> harmless. Same at bottom edge for y.
        a0[p] = inreg ? (ay0 * RW + ax0) : -1;
        a1[p] = ay1 * RW + ax0;
    }

    const float* iplane = input + (size_t)b * C * HW;
    float* oplane = out + (size_t)b * C * HW;

    // async stage of channel c (6 wave-instrs, 12 rows/wave)
    auto stage = [&](int c) {
        const float* gc = iplane + (size_t)c * HW;
        #pragma unroll
        for (int i = 0; i < 6; ++i) {
            __builtin_amdgcn_global_load_lds(
                (gas_u32*)(gc + soff[i]),
                (las_u32*)(&s[sr[i] * RW]),
                16, 0, 0);
        }
    };

    stage(0);
    __syncthreads();   // prologue: vmcnt(0) + barrier (buffer fully staged)

    for (int c = 0; c < C; ++c) {
        // ---- gather from LDS + FMA (results held in regs) ----
        float v[4];
        #pragma unroll
        for (int p = 0; p < 4; ++p) {
            if (a0[p] >= 0) {
                float v00 = s[a0[p]],  v01 = s[a0[p] + 1];
                float v10 = s[a1[p]],  v11 = s[a1[p] + 1];
                v[p] = wa[p] * v00 + wc_[p] * v01 + wb_[p] * v10 + wd_[p] * v11;
            } else {
                // outlier (|flow|>APRON, P ~ 2e-4/px): recompute + global gather
                int h = ty0 + rl + 8 * p;
                int w = tx0 + cl;
                int pix = h * W + w;
                float fx = flow[(b * 2 + 0) * HW + pix];
                float fy = flow[(b * 2 + 1) * HW + pix];
                float x = fminf(fmaxf((float)w + fx, 0.0f), (float)(W - 1));
                float y = fminf(fmaxf((float)h + fy, 0.0f), (float)(H - 1));
                float x0f = floorf(x), y0f = floorf(y);
                int x0 = (int)x0f, y0 = (int)y0f;
                int x1 = min(x0 + 1, W - 1), y1 = min(y0 + 1, H - 1);
                float dx = x - x0f, dy = y - y0f;
                const float* pch = iplane + (size_t)c * HW;
                v[p] = (1.f - dx) * (1.f - dy) * pch[y0 * W + x0]
                     + (1.f - dx) * dy         * pch[y1 * W + x0]
                     + dx * (1.f - dy)         * pch[y0 * W + x1]
                     + dx * dy                 * pch[y1 * W + x1];
            }
        }

        // ds_read data must be in VGPRs before the buffer is overwritten
        asm volatile("s_waitcnt lgkmcnt(0)" ::: "memory");
        __builtin_amdgcn_sched_barrier(0);
        __builtin_amdgcn_s_barrier();            // WAR: all waves done reading
        __builtin_amdgcn_sched_barrier(0);

        if (c + 1 < C) stage(c + 1);             // 6 async loads into the buffer

        float* oc = oplane + (size_t)c * HW;
        #pragma unroll
        for (int p = 0; p < 4; ++p)
            oc[opix0 + 8 * p * W] = v[p];        // 4 stores, issued AFTER stage

        if (c + 1 < C) {
            // drain the 6 stage loads; leave the 4 stores in flight
            asm volatile("s_waitcnt vmcnt(4)" ::: "memory");
            __builtin_amdgcn_sched_barrier(0);
            __builtin_amdgcn_s_barrier();        // RAW: buffer ready for c+1
            __builtin_amdgcn_sched_barrier(0);
        }
    }
}

extern "C" void kernel_launch(void* const* d_in, const int* in_sizes, int n_in,
                              void* d_out, int out_size, void* d_ws, size_t ws_size,
                              hipStream_t stream) {
    const float* input = (const float*)d_in[0];
    const float* flow  = (const float*)d_in[1];
    float* out = (float*)d_out;

    int grid = B * (H / TH) * (W / TW);   // 512 blocks -> 2 per CU
    warp_tile_kernel<<<grid, 512, 0, stream>>>(input, flow, out);
}

// Round 3
// 248.919 us; speedup vs baseline: 1.0892x; 1.0892x over previous
//
#include <hip/hip_runtime.h>

// Backward (bilinear) warp: out[b,c,h,w] = bilinear_sample(input[b,c], w+flow_x, h+flow_y)
// Shapes: input [4,32,512,512] f32, flow [4,2,512,512] f32, out [4,32,512,512] f32.
//
// R5 = R3 (64x64 tile, double-buffered global_load_lds pipeline, 95.7us) +
// R4's counted-waitcnt barrier discipline (which regressed only because its
// single buffer exposed stage latency). Per channel:
//   stage(c+1)->buf^1 ; gather(c)<-buf ; lgkmcnt(0) ; stores(c) ;
//   vmcnt(4) ; s_barrier
// - stage latency covered by the full gather phase (double buffer).
// - vmcnt(4) drains the 4 stage loads + last channel's stores (which had a
//   whole channel to retire); current stores never drained in-loop.
//   (R3's __syncthreads drained vmcnt(0) lgkmcnt(0) every channel = waited
//   on output stores ~0.5-1K cyc x 32 ch -- that's the gap this removes.)
// - ONE s_barrier per channel: lgkmcnt(0) before it makes all waves' reads
//   of buf complete (WAR for stage(c+2)); vmcnt(4) before it makes stage(c+1)
//   complete for every wave (RAW for gather(c+1)).
// - XCD-aware bijective swizzle kept from R4 (FETCH 127->87 MB).

constexpr int B = 4, C = 32, H = 512, W = 512;
constexpr int HW = H * W;
constexpr int TILE = 64;
constexpr int APRON = 31;       // covers |flow| <= 31 (3.87 sigma of N(0,8))
constexpr int RH = 128;         // staged rows  (64 + 31 + 31 + 1, padded)
constexpr int RW = 128;         // staged cols (dwords): 64 + 32 + 31 + 1 = 128
constexpr int BUF = RH * RW;    // 16384 dwords = 64 KiB per buffer

typedef __attribute__((address_space(1))) const unsigned int gas_u32;
typedef __attribute__((address_space(3))) unsigned int las_u32;

__global__ __launch_bounds__(1024, 1) void warp_tile_kernel(
    const float* __restrict__ input,
    const float* __restrict__ flow,
    float* __restrict__ out)
{
    __shared__ float s[2 * BUF];          // 128 KiB, double-buffered

    // XCD-aware bijective swizzle (256 blocks % 8 XCDs == 0):
    // each XCD gets 32 consecutive logical tiles.
    int bid0 = (int)blockIdx.x;
    int bid = (bid0 & 7) * 32 + (bid0 >> 3);

    int tx = bid & 7;                     // [b:4][ty:8][tx:8]
    int ty = (bid >> 3) & 7;
    int b  = bid >> 6;
    int tx0 = tx * TILE, ty0 = ty * TILE;

    // virtual region origin (may be out of image; staging sources are clamped
    // per-lane, and clamped/garbage cells are provably never gathered)
    int rx0 = tx0 - 32;                   // 32 keeps RW=128 & 16B alignment
    int ry0 = ty0 - APRON;

    int tid  = (int)threadIdx.x;
    int lane = tid & 63;
    int wv   = tid >> 6;                  // wave id 0..15
    int cl   = tid & 63;                  // output col within tile
    int rl   = tid >> 6;                  // output row group (rows rl + 16p)

    // ---- staging source offsets (channel-relative dword offsets, per lane) ----
    // wave wv, issue i (0..3) stages region rows r=8*wv+2*i and r+1:
    //   lanes 0..31 -> row r cols 4L..4L+3, lanes 32..63 -> row r+1.
    int soff[4];
    int sr[4];
    {
        int lrow = lane >> 5;                        // 0 or 1
        int lc   = (lane & 31) << 2;                 // 0..124
        int gcol = min(max(rx0 + lc, 0), W - 4);     // 16B-aligned, in-row
        #pragma unroll
        for (int i = 0; i < 4; ++i) {
            int r = 8 * wv + 2 * i;                  // wave-uniform
            sr[i] = r;
            int grow = min(max(ry0 + r + lrow, 0), H - 1);
            soff[i] = grow * W + gcol;
        }
    }

    // ---- per-pixel precompute (4 px/thread), reused across 32 channels ----
    float wa[4], wb_[4], wc_[4], wd_[4];
    int a0[4], a1[4];
    int opix0 = (ty0 + rl) * W + tx0 + cl;

    #pragma unroll
    for (int p = 0; p < 4; ++p) {
        int h = ty0 + rl + 16 * p;
        int w = tx0 + cl;
        int pix = h * W + w;
        float fx = flow[(b * 2 + 0) * HW + pix];
        float fy = flow[(b * 2 + 1) * HW + pix];
        float x = fminf(fmaxf((float)w + fx, 0.0f), (float)(W - 1));
        float y = fminf(fmaxf((float)h + fy, 0.0f), (float)(H - 1));
        float x0f = floorf(x), y0f = floorf(y);
        int x0 = (int)x0f, y0 = (int)y0f;
        int y1 = min(y0 + 1, H - 1);
        float dx = x - x0f, dy = y - y0f;
        // weights use UNCLAMPED x1f=x0f+1, y1f=y0f+1 (matches reference)
        wa[p]  = (1.f - dx) * (1.f - dy);
        wb_[p] = (1.f - dx) * dy;
        wc_[p] = dx * (1.f - dy);
        wd_[p] = dx * dy;
        int ax0 = x0 - rx0, ay0 = y0 - ry0, ay1 = y1 - ry0;
        // need ax0 in [0,RW-2] (reads ax0+1), ay0>=0, ay1<=RH-1
        bool inreg = (ax0 >= 0) && (ax0 <= RW - 2) && (ay0 >= 0) && (ay1 <= RH - 1);
        // at x0==x1 (image right edge) the +1 read hits a staged-garbage col,
        // but its weight wc==dx==0 -> harmless. Same at bottom edge for y.
        a0[p] = inreg ? (ay0 * RW + ax0) : -1;
        a1[p] = ay1 * RW + ax0;
    }

    const float* iplane = input + (size_t)b * C * HW;
    float* oplane = out + (size_t)b * C * HW;

    // async stage of channel c into buffer `buf` (4 wave-instrs, 8 rows/wave)
    auto stage = [&](int c, int buf) {
        const float* gc = iplane + (size_t)c * HW;
        #pragma unroll
        for (int i = 0; i < 4; ++i) {
            __builtin_amdgcn_global_load_lds(
                (gas_u32*)(gc + soff[i]),
                (las_u32*)(&s[buf * BUF + sr[i] * RW]),
                16, 0, 0);
        }
    };

    stage(0, 0);
    __syncthreads();   // prologue: vmcnt(0) + barrier (buffer 0 fully staged)

    for (int c = 0; c < C; ++c) {
        if (c + 1 < C) stage(c + 1, (c + 1) & 1);   // async prefetch, issued FIRST

        // ---- gather from LDS + FMA (results held in regs) ----
        int base = (c & 1) * BUF;
        float v[4];
        #pragma unroll
        for (int p = 0; p < 4; ++p) {
            if (a0[p] >= 0) {
                int i0 = base + a0[p], i1 = base + a1[p];
                float v00 = s[i0], v01 = s[i0 + 1];
                float v10 = s[i1], v11 = s[i1 + 1];
                v[p] = wa[p] * v00 + wc_[p] * v01 + wb_[p] * v10 + wd_[p] * v11;
            } else {
                // outlier (|flow|>APRON, P ~ 2e-4/px): recompute + global gather
                int h = ty0 + rl + 16 * p;
                int w = tx0 + cl;
                int pix = h * W + w;
                float fx = flow[(b * 2 + 0) * HW + pix];
                float fy = flow[(b * 2 + 1) * HW + pix];
                float x = fminf(fmaxf((float)w + fx, 0.0f), (float)(W - 1));
                float y = fminf(fmaxf((float)h + fy, 0.0f), (float)(H - 1));
                float x0f = floorf(x), y0f = floorf(y);
                int x0 = (int)x0f, y0 = (int)y0f;
                int x1 = min(x0 + 1, W - 1), y1 = min(y0 + 1, H - 1);
                float dx = x - x0f, dy = y - y0f;
                const float* pch = iplane + (size_t)c * HW;
                v[p] = (1.f - dx) * (1.f - dy) * pch[y0 * W + x0]
                     + (1.f - dx) * dy         * pch[y1 * W + x0]
                     + dx * (1.f - dy)         * pch[y0 * W + x1]
                     + dx * dy                 * pch[y1 * W + x1];
            }
        }

        // all ds_reads of buf are in VGPRs -> WAR-safe for stage(c+2)
        asm volatile("s_waitcnt lgkmcnt(0)" ::: "memory");
        __builtin_amdgcn_sched_barrier(0);

        float* oc = oplane + (size_t)c * HW;
        #pragma unroll
        for (int p = 0; p < 4; ++p)
            oc[opix0 + 16 * p * W] = v[p];       // stores AFTER the stage loads

        if (c + 1 < C) {
            // drain the 4 stage loads (+ previous channel's stores, long since
            // retired); leave this channel's 4 stores in flight
            asm volatile("s_waitcnt vmcnt(4)" ::: "memory");
            __builtin_amdgcn_sched_barrier(0);
            __builtin_amdgcn_s_barrier();        // RAW buf^1 staged; WAR buf read
            __builtin_amdgcn_sched_barrier(0);
        }
    }
}

extern "C" void kernel_launch(void* const* d_in, const int* in_sizes, int n_in,
                              void* d_out, int out_size, void* d_ws, size_t ws_size,
                              hipStream_t stream) {
    const float* input = (const float*)d_in[0];
    const float* flow  = (const float*)d_in[1];
    float* out = (float*)d_out;

    int grid = B * (H / TILE) * (W / TILE);   // 256 blocks -> 1 per CU
    warp_tile_kernel<<<grid, 1024, 0, stream>>>(input, flow, out);
}